// Round 21
// baseline (424.438 us; speedup 1.0000x reference)
//
#include <hip/hip_runtime.h>

typedef unsigned short u16;
typedef short sh4 __attribute__((ext_vector_type(4)));
typedef short short8 __attribute__((ext_vector_type(8)));
typedef u16 ush8 __attribute__((ext_vector_type(8)));
typedef __bf16 bf16x8 __attribute__((ext_vector_type(8)));
typedef float f32x4 __attribute__((ext_vector_type(4)));

#define NB 32
#define CDIM 384
#define NSP 2304
#define QCH 1152

__device__ __forceinline__ float b2f(u16 u) {
    union { unsigned i; float f; } v; v.i = ((unsigned)u) << 16; return v.f;
}
__device__ __forceinline__ u16 f2b(float f) {
    union { float f; unsigned i; } v; v.f = f;
    unsigned r = v.i + 0x7FFFu + ((v.i >> 16) & 1u);
    return (u16)(r >> 16);
}
__device__ __forceinline__ void gload16(const u16* g, u16* l) {
    __builtin_amdgcn_global_load_lds((const __attribute__((address_space(1))) unsigned int*)(g),
                                     (__attribute__((address_space(3))) unsigned int*)(l), 16, 0, 0);
}

// ---------------- K0: convert f32 weights to bf16 ----------
__global__ __launch_bounds__(256) void k_prep(const float* __restrict__ wqkv,
                                              const float* __restrict__ wproj,
                                              u16* __restrict__ wqkv_bf,
                                              u16* __restrict__ wproj_bf) {
    int i = blockIdx.x * 256 + threadIdx.x;
    if (i < QCH * CDIM) wqkv_bf[i] = f2b(wqkv[i]);
    if (i < CDIM * CDIM) wproj_bf[i] = f2b(wproj[i]);
}

// ---------------- K1: channel LayerNorm, single-pass register-resident, vectorized out ------
__global__ __launch_bounds__(256) void k_ln(const float* __restrict__ x,
                                            const float* __restrict__ lnw,
                                            const float* __restrict__ lnb,
                                            u16* __restrict__ xnt) {
    __shared__ float s_sum[4][64], s_sq[4][64], s_mu[64], s_rs[64];
    __shared__ u16 s_tile[64][392];   // 784B row stride: 16B aligned
    int b = blockIdx.y, n0 = blockIdx.x * 64;
    int tid = threadIdx.x, c4 = tid >> 6, nl = tid & 63;
    int cbase = c4 * 96;
    const float* xb = x + (size_t)b * CDIM * NSP + (size_t)cbase * NSP + n0 + nl;
    float v[96];
    float sum = 0.f, sq = 0.f;
#pragma unroll
    for (int j = 0; j < 96; j++) {
        v[j] = xb[(size_t)j * NSP];
        sum += v[j]; sq += v[j] * v[j];
    }
    s_sum[c4][nl] = sum; s_sq[c4][nl] = sq;
    __syncthreads();
    if (tid < 64) {
        float s = s_sum[0][tid] + s_sum[1][tid] + s_sum[2][tid] + s_sum[3][tid];
        float q = s_sq[0][tid] + s_sq[1][tid] + s_sq[2][tid] + s_sq[3][tid];
        float mu = s * (1.f / CDIM);
        float var = q * (1.f / CDIM) - mu * mu;
        s_mu[tid] = mu; s_rs[tid] = rsqrtf(var + 1e-5f);
    }
    __syncthreads();
    float mu = s_mu[nl], rs = s_rs[nl];
#pragma unroll
    for (int j = 0; j < 96; j++) {
        int c = cbase + j;
        s_tile[nl][c] = f2b((v[j] - mu) * rs * lnw[c] + lnb[c]);
    }
    __syncthreads();
    u16* o = xnt + ((size_t)b * NSP + n0) * CDIM;
    for (int i = tid; i < 64 * 48; i += 256) {
        int row = i / 48, c8 = i % 48;
        *(short8*)(o + row * CDIM + c8 * 8) = *(const short8*)(&s_tile[row][c8 * 8]);
    }
}

// ---------------- K2/K9 v3 (FROZEN): GEMM, gload_lds + XCD panel-grouping + coalesced C -----
__global__ __launch_bounds__(256) void k_gemm(const u16* __restrict__ A,
                                              const u16* __restrict__ Bt,
                                              void* __restrict__ Cmat, int M, int f32out) {
    __shared__ __align__(16) u16 S[128 * 128];   // main loop: As=S, Bs=S+8192; epilogue: C tile
    u16* As = S;
    u16* Bs = S + 8192;
    int tid = threadIdx.x;
    int nym = gridDim.y;
    int flat = blockIdx.x + gridDim.x * (blockIdx.y + nym * blockIdx.z);
    int p = flat & 7, q = flat >> 3;
    int bym = q % nym;
    int panel = (q / nym) * 8 + p;
    int bxn = panel % 18, bz = panel / 18;
    int wave = tid >> 6, lane = tid & 63, wr = wave >> 1, wc = wave & 1;
    int lr = lane & 15, lk = lane >> 4;
    f32x4 acc[4][4];
#pragma unroll
    for (int m = 0; m < 4; m++)
#pragma unroll
        for (int n = 0; n < 4; n++) acc[m][n] = (f32x4){0.f, 0.f, 0.f, 0.f};
    int coloff = ((lane & 7) ^ (lane >> 3)) * 8;   // pre-swizzled source col-group
    int rsub = lane >> 3;                          // row within 8-row segment
    const u16* Ag = A + (size_t)(bym * 128 + wave * 32 + rsub) * 384 + coloff;
    const u16* Bg = Bt + ((size_t)bz * NSP + bxn * 128 + wave * 32 + rsub) * 384 + coloff;
    u16* Al = As + (wave * 4) * 512;   // wave-uniform LDS base, 4 segments x 1KB
    u16* Bl = Bs + (wave * 4) * 512;
    for (int k0 = 0; k0 < 384; k0 += 64) {
#pragma unroll
        for (int i = 0; i < 4; i++) {
            gload16(Ag + (size_t)(i * 8) * 384 + k0, Al + i * 512);
            gload16(Bg + (size_t)(i * 8) * 384 + k0, Bl + i * 512);
        }
        __syncthreads();
        short8 bfr[4][2];
#pragma unroll
        for (int n = 0; n < 4; n++) {
            int row = wc * 64 + n * 16 + lr;
#pragma unroll
            for (int h = 0; h < 2; h++)
                bfr[n][h] = *(const short8*)(Bs + row * 64 + ((h * 4 + lk) ^ (lr & 7)) * 8);
        }
#pragma unroll
        for (int m = 0; m < 4; m++) {
            int row = wr * 64 + m * 16 + lr;
            short8 a0 = *(const short8*)(As + row * 64 + ((lk) ^ (lr & 7)) * 8);
            short8 a1 = *(const short8*)(As + row * 64 + ((4 + lk) ^ (lr & 7)) * 8);
#pragma unroll
            for (int n = 0; n < 4; n++) {
                acc[m][n] = __builtin_amdgcn_mfma_f32_16x16x32_bf16(
                    __builtin_bit_cast(bf16x8, a0), __builtin_bit_cast(bf16x8, bfr[n][0]),
                    acc[m][n], 0, 0, 0);
                acc[m][n] = __builtin_amdgcn_mfma_f32_16x16x32_bf16(
                    __builtin_bit_cast(bf16x8, a1), __builtin_bit_cast(bf16x8, bfr[n][1]),
                    acc[m][n], 0, 0, 0);
            }
        }
        __syncthreads();
    }
    if (!f32out) {
        // bf16: bounce through LDS (128x128 u16), then fully-coalesced short8 stores
#pragma unroll
        for (int m = 0; m < 4; m++)
#pragma unroll
            for (int n = 0; n < 4; n++)
#pragma unroll
                for (int r = 0; r < 4; r++)
                    S[(wr * 64 + m * 16 + lk * 4 + r) * 128 + wc * 64 + n * 16 + lr] =
                        f2b(acc[m][n][r]);
        __syncthreads();
        u16* Cg = (u16*)Cmat + ((size_t)bz * M + bym * 128) * NSP + bxn * 128;
#pragma unroll
        for (int i = 0; i < 8; i++) {
            int f = tid + i * 256;
            int row = f >> 4, c8 = f & 15;
            *(short8*)(Cg + (size_t)row * NSP + c8 * 8) = *(const short8*)(&S[row * 128 + c8 * 8]);
        }
    } else {
        // f32: two 64-row halves through LDS (32KB = 64x128 f32)
        float* Sf = (float*)S;
        float* Cg = (float*)Cmat + ((size_t)bz * M + bym * 128) * NSP + bxn * 128;
#pragma unroll
        for (int half = 0; half < 2; half++) {
            if (wr == half) {
#pragma unroll
                for (int m = 0; m < 4; m++)
#pragma unroll
                    for (int n = 0; n < 4; n++)
#pragma unroll
                        for (int r = 0; r < 4; r++)
                            Sf[(m * 16 + lk * 4 + r) * 128 + wc * 64 + n * 16 + lr] = acc[m][n][r];
            }
            __syncthreads();
#pragma unroll
            for (int i = 0; i < 8; i++) {
                int f = tid + i * 256;
                int row = f >> 5, c4 = f & 31;
                *(f32x4*)(Cg + (size_t)(half * 64 + row) * NSP + c4 * 4) =
                    *(const f32x4*)(&Sf[row * 128 + c4 * 4]);
            }
            __syncthreads();
        }
    }
}

// ---------------- K3 v3: 3x3 depthwise IN-PLACE, LDS-bounced coalesced I/O ----------------
__global__ __launch_bounds__(192) void k_dw3(u16* __restrict__ qkv,
                                             const float* __restrict__ wdw,
                                             float* __restrict__ sumsq) {
    __shared__ u16 s_in[4 * 2304];
    __shared__ float s_part[192];
    int bx = blockIdx.x, b = blockIdx.y, tid = threadIdx.x;
    u16* gbase = qkv + ((size_t)b * QCH + bx * 4) * NSP;
#pragma unroll
    for (int i = 0; i < 6; i++) {
        int c = tid + i * 192;
        *(ush8*)(&s_in[c * 8]) = *(const ush8*)(gbase + c * 8);
    }
    int p = tid / 48, y = tid % 48;
    int ch = bx * 4 + p;
    float w[9];
#pragma unroll
    for (int i = 0; i < 9; i++) w[i] = wdw[ch * 9 + i];
    __syncthreads();
    const u16* L = &s_in[p * 2304];
    ush8 r0[6], r1[6], r2[6];
#pragma unroll
    for (int o = 0; o < 6; o++) {
        r1[o] = *(const ush8*)(L + y * 48 + o * 8);
        if (y > 0)  r0[o] = *(const ush8*)(L + (y - 1) * 48 + o * 8); else r0[o] = 0;
        if (y < 47) r2[o] = *(const ush8*)(L + (y + 1) * 48 + o * 8); else r2[o] = 0;
    }
    float ss = 0.f;
    short8 outv[6];
#pragma unroll
    for (int g = 0; g < 6; g++) {
        float a0[10], a1[10], a2[10];
#pragma unroll
        for (int j = 0; j < 10; j++) {
            int xi = g * 8 - 1 + j;
            if (xi < 0 || xi >= 48) { a0[j] = 0.f; a1[j] = 0.f; a2[j] = 0.f; }
            else {
                a0[j] = b2f(r0[xi >> 3][xi & 7]);
                a1[j] = b2f(r1[xi >> 3][xi & 7]);
                a2[j] = b2f(r2[xi >> 3][xi & 7]);
            }
        }
        union { u16 u[8]; short8 v; } pk;
#pragma unroll
        for (int x = 0; x < 8; x++) {
            float o = a0[x] * w[0] + a0[x + 1] * w[1] + a0[x + 2] * w[2]
                    + a1[x] * w[3] + a1[x + 1] * w[4] + a1[x + 2] * w[5]
                    + a2[x] * w[6] + a2[x + 1] * w[7] + a2[x + 2] * w[8];
            ss += o * o;
            pk.u[x] = f2b(o);
        }
        outv[g] = pk.v;
    }
    s_part[tid] = ss;
    __syncthreads();   // all LDS reads done; safe to overwrite
#pragma unroll
    for (int g = 0; g < 6; g++)
        *(short8*)(&s_in[p * 2304 + y * 48 + g * 8]) = outv[g];
    __syncthreads();
#pragma unroll
    for (int i = 0; i < 6; i++) {
        int c = tid + i * 192;
        *(ush8*)(gbase + c * 8) = *(const ush8*)(&s_in[c * 8]);
    }
    if (bx < 192 && tid < 4) {
        float s = 0.f;
        for (int i = 0; i < 48; i++) s += s_part[tid * 48 + i];
        sumsq[b * 768 + bx * 4 + tid] = s;
    }
}

// ---------------- K5: attn via MFMA, split-K over 8 waves; OUT: bf16 [c][d]; inline rsqrt ---
__global__ __launch_bounds__(512) void k_attn(const u16* __restrict__ qkv,
                                              const float* __restrict__ sumsq,
                                              const float* __restrict__ temp,
                                              u16* __restrict__ attn) {
    __shared__ float s_part[8][48 * 48];
    int h = blockIdx.x, b = blockIdx.y, tid = threadIdx.x;
    int wave = tid >> 6, lane = tid & 63;
    int lr = lane & 15, lk = lane >> 4;
    const u16* qp = qkv + ((size_t)b * QCH + h * 48) * NSP;
    const u16* kp = qkv + ((size_t)b * QCH + 384 + h * 48) * NSP;
    f32x4 acc[3][3];
#pragma unroll
    for (int m = 0; m < 3; m++)
#pragma unroll
        for (int n = 0; n < 3; n++) acc[m][n] = (f32x4){0.f, 0.f, 0.f, 0.f};
    int k0 = wave * 288 + lk * 8;
    short8 af[3], bf[3], afn[3], bfn[3];
#pragma unroll
    for (int m = 0; m < 3; m++) {
        af[m] = *(const short8*)(qp + (size_t)(m * 16 + lr) * NSP + k0);
        bf[m] = *(const short8*)(kp + (size_t)(m * 16 + lr) * NSP + k0);
    }
    for (int s = 0; s < 9; s++) {
        if (s < 8) {
#pragma unroll
            for (int m = 0; m < 3; m++) {
                afn[m] = *(const short8*)(qp + (size_t)(m * 16 + lr) * NSP + k0 + 32 * (s + 1));
                bfn[m] = *(const short8*)(kp + (size_t)(m * 16 + lr) * NSP + k0 + 32 * (s + 1));
            }
        }
#pragma unroll
        for (int m = 0; m < 3; m++)
#pragma unroll
            for (int n = 0; n < 3; n++)
                acc[m][n] = __builtin_amdgcn_mfma_f32_16x16x32_bf16(
                    __builtin_bit_cast(bf16x8, af[m]), __builtin_bit_cast(bf16x8, bf[n]),
                    acc[m][n], 0, 0, 0);
#pragma unroll
        for (int m = 0; m < 3; m++) { af[m] = afn[m]; bf[m] = bfn[m]; }
    }
#pragma unroll
    for (int m = 0; m < 3; m++)
#pragma unroll
        for (int n = 0; n < 3; n++)
#pragma unroll
            for (int r = 0; r < 4; r++)
                s_part[wave][(m * 16 + lk * 4 + r) * 48 + n * 16 + lr] = acc[m][n][r];
    __syncthreads();
    float th = temp[h];
    const float* sqv = sumsq + b * 768 + h * 48;
    const float* skv = sumsq + b * 768 + 384 + h * 48;
    u16* ap = attn + ((size_t)(b * 8 + h)) * NSP;
    for (int f = tid; f < 2304; f += 512) {
        int c = f / 48, d = f % 48;
        float v = 0.f;
#pragma unroll
        for (int wv = 0; wv < 8; wv++) v += s_part[wv][f];
        float rq = 1.f / fmaxf(sqrtf(sqv[c]), 1e-12f);
        float rk = 1.f / fmaxf(sqrtf(skv[d]), 1e-12f);
        v *= th * rq * rk;
        ap[f] = f2b(fmaxf(v, 0.f));   // bf16, [c][d]
    }
}

// ---------------- K6: high-pass depthwise (3/5/7), merged single kernel ----------
template<int KS, int CH0, int NCH>
__device__ __forceinline__ void hp_body(int g, const u16* __restrict__ qkv,
                                        const float* __restrict__ wk,
                                        const float* __restrict__ bk,
                                        u16* __restrict__ hp) {
    constexpr int PAD = KS / 2;
    constexpr int NIN = 8 + 2 * PAD;
    int t = g * 256 + threadIdx.x;
    int y = t % 48;
    int rem = t / 48;
    int chl = rem % NCH;
    int b = rem / NCH;
    int ch = CH0 + chl;
    const u16* src = qkv + ((size_t)b * QCH + 768 + ch) * NSP;
    float bias = bk[chl];
    float acc[48];
#pragma unroll
    for (int i = 0; i < 48; i++) acc[i] = bias;
    for (int dy = 0; dy < KS; dy++) {
        int yy = y - PAD + dy;
        if (yy < 0 || yy >= 48) continue;
        ush8 r[6];
#pragma unroll
        for (int o = 0; o < 6; o++) r[o] = *(const ush8*)(src + yy * 48 + o * 8);
        float wr[KS];
#pragma unroll
        for (int dx = 0; dx < KS; dx++) wr[dx] = wk[chl * KS * KS + dy * KS + dx];
#pragma unroll
        for (int g2 = 0; g2 < 6; g2++) {
            float a[NIN];
#pragma unroll
            for (int j = 0; j < NIN; j++) {
                int xi = g2 * 8 - PAD + j;
                a[j] = (xi < 0 || xi >= 48) ? 0.f : b2f(r[xi >> 3][xi & 7]);
            }
#pragma unroll
            for (int x = 0; x < 8; x++) {
                float s = 0.f;
#pragma unroll
                for (int dx = 0; dx < KS; dx++) s += a[x + dx] * wr[dx];
                acc[g2 * 8 + x] += s;
            }
        }
    }
    u16* dst = hp + ((size_t)b * CDIM + ch) * NSP + y * 48;
#pragma unroll
    for (int g2 = 0; g2 < 6; g2++) {
        union { u16 u[8]; short8 v; } pk;
#pragma unroll
        for (int x = 0; x < 8; x++) pk.u[x] = f2b(acc[g2 * 8 + x]);
        *(short8*)(dst + g2 * 8) = pk.v;
    }
}

__global__ __launch_bounds__(256) void k_hp(const u16* __restrict__ qkv,
                                            const float* __restrict__ w3, const float* __restrict__ b3,
                                            const float* __restrict__ w5, const float* __restrict__ b5,
                                            const float* __restrict__ w7, const float* __restrict__ b7,
                                            u16* __restrict__ hp) {
    int g = blockIdx.x;
    if (g < 864)       hp_body<3, 0, 144>(g, qkv, w3, b3, hp);
    else if (g < 1728) hp_body<5, 144, 144>(g - 864, qkv, w5, b5, hp);
    else               hp_body<7, 288, 96>(g - 1728, qkv, w7, b7, hp);
}

// ---------------- K7 v2: adaptive avg pool, LDS-staged coalesced ----------------
__global__ __launch_bounds__(64) void k_pool(const u16* __restrict__ qkv,
                                             float* __restrict__ pooled) {
    int c = blockIdx.x, b = blockIdx.y, tid = threadIdx.x;
    int s = 2 * (c / 96) + 1;  // 1,3,5,7
    __shared__ u16 s_p[2304];
    __shared__ float rp[48][7];
    const u16* src = qkv + ((size_t)b * QCH + 768 + c) * NSP;
    for (int f = tid; f < 288; f += 64)
        *(ush8*)(&s_p[f * 8]) = *(const ush8*)(src + f * 8);
    __syncthreads();
    if (tid < 48) {
        for (int q = 0; q < s; q++) {
            int a = q * 48 / s, e = ((q + 1) * 48 + s - 1) / s;
            float sum = 0.f;
            for (int xx = a; xx < e; xx++) sum += b2f(s_p[tid * 48 + xx]);
            rp[tid][q] = sum / (float)(e - a);
        }
    }
    __syncthreads();
    if (tid < s * s) {
        int p = tid / s, q = tid % s;
        int a = p * 48 / s, e = ((p + 1) * 48 + s - 1) / s;
        float sum = 0.f;
        for (int r = a; r < e; r++) sum += rp[r][q];
        pooled[((size_t)b * CDIM + c) * 49 + tid] = sum / (float)(e - a);
    }
}

// ---------------- K8 v8: persistent-ish attn@v + epilogue; 6 blocks/CU, 6 chunks each ------
__global__ __launch_bounds__(256) void k_out(const u16* __restrict__ qkv,
                                             const u16* __restrict__ attn,
                                             const float* __restrict__ sumsq,
                                             const u16* __restrict__ hp,
                                             const float* __restrict__ pooled,
                                             u16* __restrict__ tmpt) {
    int ncg = blockIdx.x, h = blockIdx.y, b = blockIdx.z, tid = threadIdx.x;
    __shared__ __align__(16) u16 s_at[48 * 72];   // [c][72], cols 48..63 zero-padded
    __shared__ __align__(16) u16 s_vt[64 * 72];   // [nn][72], cols 48..63 zero-padded
    __shared__ float s_pool[48 * 49];
    __shared__ float s_rq[48];
    int s = 2 * (h / 2) + 1, ss2 = s * s;
    // ---- one-time staging (consumed after first in-loop barrier) ----
    if (tid < 96) {            // s_at pad cols 48..63
        int c = tid >> 1, col8 = 48 + (tid & 1) * 8;
        *(ush8*)(&s_at[c * 72 + col8]) = (ush8)0;
    }
    if (tid < 128) {           // s_vt pad cols 48..63 (never overwritten in loop)
        int nn = tid >> 1, col8 = 48 + (tid & 1) * 8;
        *(ush8*)(&s_vt[nn * 72 + col8]) = (ush8)0;
    }
    const u16* ag = attn + ((size_t)(b * 8 + h)) * NSP;
    for (int f = tid; f < 288; f += 256) {
        int c = f / 6, j = f % 6;
        *(ush8*)(&s_at[c * 72 + j * 8]) = *(const ush8*)(ag + c * 48 + j * 8);
    }
    const float* psrc = pooled + ((size_t)b * CDIM + h * 48) * 49;
    for (int f = tid; f < 48 * ss2; f += 256) {
        int c = f / ss2, idx = f - c * ss2;
        s_pool[c * 49 + idx] = psrc[c * 49 + idx];
    }
    if (tid < 48) s_rq[tid] = 1.f / fmaxf(sqrtf(sumsq[b * 768 + h * 48 + tid]), 1e-12f);

    int wave = tid >> 6, lane = tid & 63, lr = lane & 15, lk = lane >> 4;
    const u16* vbase = qkv + ((size_t)b * QCH + 768 + h * 48) * NSP;
    const u16* qbase = qkv + ((size_t)b * QCH + h * 48) * NSP;
    const u16* hbase = hp + ((size_t)b * CDIM + h * 48) * NSP;
    const float inv = 0.14433756729740643f;  // 48^-0.5
    short8 afr[3][2];

    for (int it = 0; it < 6; it++) {
        int n0 = (ncg * 6 + it) * 64;
        // stage v transpose for this chunk (d<48 region only)
        for (int f = tid; f < 3072; f += 256) {
            int d = f >> 6, nn = f & 63;
            s_vt[nn * 72 + d] = vbase[(size_t)d * NSP + n0 + nn];
        }
        __syncthreads();
        if (it == 0) {
#pragma unroll
            for (int m = 0; m < 3; m++)
#pragma unroll
                for (int ks = 0; ks < 2; ks++)
                    afr[m][ks] = *(const short8*)(&s_at[(m * 16 + lr) * 72 + ks * 32 + lk * 8]);
        }
        short8 b0 = *(const short8*)(&s_vt[(wave * 16 + lr) * 72 + lk * 8]);
        short8 b1 = *(const short8*)(&s_vt[(wave * 16 + lr) * 72 + 32 + lk * 8]);
        f32x4 acc[3];
#pragma unroll
        for (int m = 0; m < 3; m++) {
            acc[m] = (f32x4){0.f, 0.f, 0.f, 0.f};
            acc[m] = __builtin_amdgcn_mfma_f32_16x16x32_bf16(
                __builtin_bit_cast(bf16x8, afr[m][0]), __builtin_bit_cast(bf16x8, b0),
                acc[m], 0, 0, 0);
            acc[m] = __builtin_amdgcn_mfma_f32_16x16x32_bf16(
                __builtin_bit_cast(bf16x8, afr[m][1]), __builtin_bit_cast(bf16x8, b1),
                acc[m], 0, 0, 0);
        }
        int nl_e = wave * 16 + lr;
        int n = n0 + nl_e;
        int y = n / 48, xx = n % 48;
        int iy0 = 0, iy1 = 0, ix0 = 0, ix1 = 0;
        float fy = 0.f, fx = 0.f;
        if (s > 1) {
            float syf = (y + 0.5f) * s * (1.f / 48.f) - 0.5f;
            iy0 = (int)floorf(syf); fy = syf - (float)iy0;
            iy1 = min(iy0 + 1, s - 1); iy0 = max(iy0, 0);
            float sxf = (xx + 0.5f) * s * (1.f / 48.f) - 0.5f;
            ix0 = (int)floorf(sxf); fx = sxf - (float)ix0;
            ix1 = min(ix0 + 1, s - 1); ix0 = max(ix0, 0);
        }
        const u16* qp = qbase + n;
        const u16* hq = hbase + n;
        u16* tp = tmpt + ((size_t)b * NSP + n) * CDIM + h * 48;
#pragma unroll
        for (int m = 0; m < 3; m++) {
            int cb = m * 16 + lk * 4;
            union { u16 u[4]; sh4 v; } pk;
#pragma unroll
            for (int r = 0; r < 4; r++) {
                int ch = cb + r;
                float qv = b2f(qp[(size_t)ch * NSP]);
                float hv = b2f(hq[(size_t)ch * NSP]);
                const float* P = &s_pool[ch * 49];
                float lp;
                if (s == 1) lp = P[0];
                else lp = (1.f - fy) * ((1.f - fx) * P[iy0 * s + ix0] + fx * P[iy0 * s + ix1])
                        + fy * ((1.f - fx) * P[iy1 * s + ix0] + fx * P[iy1 * s + ix1]);
                lp = fmaxf(lp, 0.f);
                pk.u[r] = f2b(inv * acc[m][r] + qv * s_rq[ch] * hv + lp);
            }
            *(sh4*)(tp + cb) = pk.v;
        }
        __syncthreads();   // protect s_vt before next chunk's writes
    }
}

extern "C" void kernel_launch(void* const* d_in, const int* in_sizes, int n_in,
                              void* d_out, int out_size, void* d_ws, size_t ws_size,
                              hipStream_t stream) {
    const float* x    = (const float*)d_in[0];
    const float* lnw  = (const float*)d_in[1];
    const float* lnb  = (const float*)d_in[2];
    const float* wqkv = (const float*)d_in[3];
    const float* wdw  = (const float*)d_in[4];
    const float* temp = (const float*)d_in[5];
    const float* w3   = (const float*)d_in[6];
    const float* b3   = (const float*)d_in[7];
    const float* w5   = (const float*)d_in[8];
    const float* b5   = (const float*)d_in[9];
    const float* w7   = (const float*)d_in[10];
    const float* b7   = (const float*)d_in[11];
    const float* wproj= (const float*)d_in[12];
    float* out = (float*)d_out;

    char* w = (char*)d_ws;
    const size_t SZ_XNT = (size_t)NB * NSP * CDIM * 2;   // 56,623,104  (xn; reused as tmpt)
    const size_t SZ_QKV = (size_t)NB * QCH * NSP * 2;    // 169,869,312
    u16* xnt      = (u16*)w;
    u16* qkvb     = (u16*)(w + SZ_XNT);                  // gemm out; dw3 in-place
    u16* hpb      = (u16*)(w + SZ_XNT + SZ_QKV);         // hp output
    char* tail    = w + SZ_XNT + SZ_QKV + (size_t)NB * CDIM * NSP * 2;
    float* sumsq  = (float*)tail;
    u16*  attnb   = (u16*)(sumsq + NB * 768);            // bf16 [c][d]
    float* pooled = (float*)(attnb + (size_t)NB * 8 * NSP);
    u16* wqkv_bf  = (u16*)(pooled + (size_t)NB * CDIM * 49);
    u16* wproj_bf = wqkv_bf + (size_t)QCH * CDIM;
    u16* tmpt = xnt;

    k_prep <<<dim3((QCH * CDIM + 255) / 256), 256, 0, stream>>>(wqkv, wproj, wqkv_bf, wproj_bf);
    k_ln   <<<dim3(36, NB), 256, 0, stream>>>(x, lnw, lnb, xnt);
    k_gemm <<<dim3(18, 9, NB), 256, 0, stream>>>(wqkv_bf, xnt, qkvb, QCH, 0);
    k_dw3  <<<dim3(288, NB), 192, 0, stream>>>(qkvb, wdw, sumsq);
    k_attn <<<dim3(8, NB), 512, 0, stream>>>(qkvb, sumsq, temp, attnb);
    k_hp   <<<dim3(2304), 256, 0, stream>>>(qkvb, w3, b3, w5, b5, w7, b7, hpb);
    k_pool <<<dim3(CDIM, NB), 64, 0, stream>>>(qkvb, pooled);
    k_out  <<<dim3(6, 8, NB), 256, 0, stream>>>(qkvb, attnb, sumsq, hpb, pooled, tmpt);
    k_gemm <<<dim3(18, 3, NB), 256, 0, stream>>>(wproj_bf, tmpt, out, CDIM, 1);
}

// Round 22
// 403.905 us; speedup vs baseline: 1.0508x; 1.0508x over previous
//
#include <hip/hip_runtime.h>

typedef unsigned short u16;
typedef short sh4 __attribute__((ext_vector_type(4)));
typedef short short8 __attribute__((ext_vector_type(8)));
typedef u16 ush8 __attribute__((ext_vector_type(8)));
typedef __bf16 bf16x8 __attribute__((ext_vector_type(8)));
typedef float f32x4 __attribute__((ext_vector_type(4)));

#define NB 32
#define CDIM 384
#define NSP 2304
#define QCH 1152

__device__ __forceinline__ float b2f(u16 u) {
    union { unsigned i; float f; } v; v.i = ((unsigned)u) << 16; return v.f;
}
__device__ __forceinline__ u16 f2b(float f) {
    union { float f; unsigned i; } v; v.f = f;
    unsigned r = v.i + 0x7FFFu + ((v.i >> 16) & 1u);
    return (u16)(r >> 16);
}
__device__ __forceinline__ void gload16(const u16* g, u16* l) {
    __builtin_amdgcn_global_load_lds((const __attribute__((address_space(1))) unsigned int*)(g),
                                     (__attribute__((address_space(3))) unsigned int*)(l), 16, 0, 0);
}

// ---------------- K0: convert f32 weights to bf16 ----------
__global__ __launch_bounds__(256) void k_prep(const float* __restrict__ wqkv,
                                              const float* __restrict__ wproj,
                                              u16* __restrict__ wqkv_bf,
                                              u16* __restrict__ wproj_bf) {
    int i = blockIdx.x * 256 + threadIdx.x;
    if (i < QCH * CDIM) wqkv_bf[i] = f2b(wqkv[i]);
    if (i < CDIM * CDIM) wproj_bf[i] = f2b(wproj[i]);
}

// ---------------- K1: channel LayerNorm, single-pass register-resident, vectorized out ------
__global__ __launch_bounds__(256) void k_ln(const float* __restrict__ x,
                                            const float* __restrict__ lnw,
                                            const float* __restrict__ lnb,
                                            u16* __restrict__ xnt) {
    __shared__ float s_sum[4][64], s_sq[4][64], s_mu[64], s_rs[64];
    __shared__ u16 s_tile[64][392];   // 784B row stride: 16B aligned
    int b = blockIdx.y, n0 = blockIdx.x * 64;
    int tid = threadIdx.x, c4 = tid >> 6, nl = tid & 63;
    int cbase = c4 * 96;
    const float* xb = x + (size_t)b * CDIM * NSP + (size_t)cbase * NSP + n0 + nl;
    float v[96];
    float sum = 0.f, sq = 0.f;
#pragma unroll
    for (int j = 0; j < 96; j++) {
        v[j] = xb[(size_t)j * NSP];
        sum += v[j]; sq += v[j] * v[j];
    }
    s_sum[c4][nl] = sum; s_sq[c4][nl] = sq;
    __syncthreads();
    if (tid < 64) {
        float s = s_sum[0][tid] + s_sum[1][tid] + s_sum[2][tid] + s_sum[3][tid];
        float q = s_sq[0][tid] + s_sq[1][tid] + s_sq[2][tid] + s_sq[3][tid];
        float mu = s * (1.f / CDIM);
        float var = q * (1.f / CDIM) - mu * mu;
        s_mu[tid] = mu; s_rs[tid] = rsqrtf(var + 1e-5f);
    }
    __syncthreads();
    float mu = s_mu[nl], rs = s_rs[nl];
#pragma unroll
    for (int j = 0; j < 96; j++) {
        int c = cbase + j;
        s_tile[nl][c] = f2b((v[j] - mu) * rs * lnw[c] + lnb[c]);
    }
    __syncthreads();
    u16* o = xnt + ((size_t)b * NSP + n0) * CDIM;
    for (int i = tid; i < 64 * 48; i += 256) {
        int row = i / 48, c8 = i % 48;
        *(short8*)(o + row * CDIM + c8 * 8) = *(const short8*)(&s_tile[row][c8 * 8]);
    }
}

// ---------------- K2/K9 v3 (FROZEN): GEMM, gload_lds + XCD panel-grouping + coalesced C -----
__global__ __launch_bounds__(256) void k_gemm(const u16* __restrict__ A,
                                              const u16* __restrict__ Bt,
                                              void* __restrict__ Cmat, int M, int f32out) {
    __shared__ __align__(16) u16 S[128 * 128];   // main loop: As=S, Bs=S+8192; epilogue: C tile
    u16* As = S;
    u16* Bs = S + 8192;
    int tid = threadIdx.x;
    int nym = gridDim.y;
    int flat = blockIdx.x + gridDim.x * (blockIdx.y + nym * blockIdx.z);
    int p = flat & 7, q = flat >> 3;
    int bym = q % nym;
    int panel = (q / nym) * 8 + p;
    int bxn = panel % 18, bz = panel / 18;
    int wave = tid >> 6, lane = tid & 63, wr = wave >> 1, wc = wave & 1;
    int lr = lane & 15, lk = lane >> 4;
    f32x4 acc[4][4];
#pragma unroll
    for (int m = 0; m < 4; m++)
#pragma unroll
        for (int n = 0; n < 4; n++) acc[m][n] = (f32x4){0.f, 0.f, 0.f, 0.f};
    int coloff = ((lane & 7) ^ (lane >> 3)) * 8;   // pre-swizzled source col-group
    int rsub = lane >> 3;                          // row within 8-row segment
    const u16* Ag = A + (size_t)(bym * 128 + wave * 32 + rsub) * 384 + coloff;
    const u16* Bg = Bt + ((size_t)bz * NSP + bxn * 128 + wave * 32 + rsub) * 384 + coloff;
    u16* Al = As + (wave * 4) * 512;   // wave-uniform LDS base, 4 segments x 1KB
    u16* Bl = Bs + (wave * 4) * 512;
    for (int k0 = 0; k0 < 384; k0 += 64) {
#pragma unroll
        for (int i = 0; i < 4; i++) {
            gload16(Ag + (size_t)(i * 8) * 384 + k0, Al + i * 512);
            gload16(Bg + (size_t)(i * 8) * 384 + k0, Bl + i * 512);
        }
        __syncthreads();
        short8 bfr[4][2];
#pragma unroll
        for (int n = 0; n < 4; n++) {
            int row = wc * 64 + n * 16 + lr;
#pragma unroll
            for (int h = 0; h < 2; h++)
                bfr[n][h] = *(const short8*)(Bs + row * 64 + ((h * 4 + lk) ^ (lr & 7)) * 8);
        }
#pragma unroll
        for (int m = 0; m < 4; m++) {
            int row = wr * 64 + m * 16 + lr;
            short8 a0 = *(const short8*)(As + row * 64 + ((lk) ^ (lr & 7)) * 8);
            short8 a1 = *(const short8*)(As + row * 64 + ((4 + lk) ^ (lr & 7)) * 8);
#pragma unroll
            for (int n = 0; n < 4; n++) {
                acc[m][n] = __builtin_amdgcn_mfma_f32_16x16x32_bf16(
                    __builtin_bit_cast(bf16x8, a0), __builtin_bit_cast(bf16x8, bfr[n][0]),
                    acc[m][n], 0, 0, 0);
                acc[m][n] = __builtin_amdgcn_mfma_f32_16x16x32_bf16(
                    __builtin_bit_cast(bf16x8, a1), __builtin_bit_cast(bf16x8, bfr[n][1]),
                    acc[m][n], 0, 0, 0);
            }
        }
        __syncthreads();
    }
    if (!f32out) {
        // bf16: bounce through LDS (128x128 u16), then fully-coalesced short8 stores
#pragma unroll
        for (int m = 0; m < 4; m++)
#pragma unroll
            for (int n = 0; n < 4; n++)
#pragma unroll
                for (int r = 0; r < 4; r++)
                    S[(wr * 64 + m * 16 + lk * 4 + r) * 128 + wc * 64 + n * 16 + lr] =
                        f2b(acc[m][n][r]);
        __syncthreads();
        u16* Cg = (u16*)Cmat + ((size_t)bz * M + bym * 128) * NSP + bxn * 128;
#pragma unroll
        for (int i = 0; i < 8; i++) {
            int f = tid + i * 256;
            int row = f >> 4, c8 = f & 15;
            *(short8*)(Cg + (size_t)row * NSP + c8 * 8) = *(const short8*)(&S[row * 128 + c8 * 8]);
        }
    } else {
        // f32: two 64-row halves through LDS (32KB = 64x128 f32)
        float* Sf = (float*)S;
        float* Cg = (float*)Cmat + ((size_t)bz * M + bym * 128) * NSP + bxn * 128;
#pragma unroll
        for (int half = 0; half < 2; half++) {
            if (wr == half) {
#pragma unroll
                for (int m = 0; m < 4; m++)
#pragma unroll
                    for (int n = 0; n < 4; n++)
#pragma unroll
                        for (int r = 0; r < 4; r++)
                            Sf[(m * 16 + lk * 4 + r) * 128 + wc * 64 + n * 16 + lr] = acc[m][n][r];
            }
            __syncthreads();
#pragma unroll
            for (int i = 0; i < 8; i++) {
                int f = tid + i * 256;
                int row = f >> 5, c4 = f & 31;
                *(f32x4*)(Cg + (size_t)(half * 64 + row) * NSP + c4 * 4) =
                    *(const f32x4*)(&Sf[row * 128 + c4 * 4]);
            }
            __syncthreads();
        }
    }
}

// ---------------- K3 v3: 3x3 depthwise IN-PLACE, LDS-bounced coalesced I/O ----------------
__global__ __launch_bounds__(192) void k_dw3(u16* __restrict__ qkv,
                                             const float* __restrict__ wdw,
                                             float* __restrict__ sumsq) {
    __shared__ u16 s_in[4 * 2304];
    __shared__ float s_part[192];
    int bx = blockIdx.x, b = blockIdx.y, tid = threadIdx.x;
    u16* gbase = qkv + ((size_t)b * QCH + bx * 4) * NSP;
#pragma unroll
    for (int i = 0; i < 6; i++) {
        int c = tid + i * 192;
        *(ush8*)(&s_in[c * 8]) = *(const ush8*)(gbase + c * 8);
    }
    int p = tid / 48, y = tid % 48;
    int ch = bx * 4 + p;
    float w[9];
#pragma unroll
    for (int i = 0; i < 9; i++) w[i] = wdw[ch * 9 + i];
    __syncthreads();
    const u16* L = &s_in[p * 2304];
    ush8 r0[6], r1[6], r2[6];
#pragma unroll
    for (int o = 0; o < 6; o++) {
        r1[o] = *(const ush8*)(L + y * 48 + o * 8);
        if (y > 0)  r0[o] = *(const ush8*)(L + (y - 1) * 48 + o * 8); else r0[o] = 0;
        if (y < 47) r2[o] = *(const ush8*)(L + (y + 1) * 48 + o * 8); else r2[o] = 0;
    }
    float ss = 0.f;
    short8 outv[6];
#pragma unroll
    for (int g = 0; g < 6; g++) {
        float a0[10], a1[10], a2[10];
#pragma unroll
        for (int j = 0; j < 10; j++) {
            int xi = g * 8 - 1 + j;
            if (xi < 0 || xi >= 48) { a0[j] = 0.f; a1[j] = 0.f; a2[j] = 0.f; }
            else {
                a0[j] = b2f(r0[xi >> 3][xi & 7]);
                a1[j] = b2f(r1[xi >> 3][xi & 7]);
                a2[j] = b2f(r2[xi >> 3][xi & 7]);
            }
        }
        union { u16 u[8]; short8 v; } pk;
#pragma unroll
        for (int x = 0; x < 8; x++) {
            float o = a0[x] * w[0] + a0[x + 1] * w[1] + a0[x + 2] * w[2]
                    + a1[x] * w[3] + a1[x + 1] * w[4] + a1[x + 2] * w[5]
                    + a2[x] * w[6] + a2[x + 1] * w[7] + a2[x + 2] * w[8];
            ss += o * o;
            pk.u[x] = f2b(o);
        }
        outv[g] = pk.v;
    }
    s_part[tid] = ss;
    __syncthreads();   // all LDS reads done; safe to overwrite
#pragma unroll
    for (int g = 0; g < 6; g++)
        *(short8*)(&s_in[p * 2304 + y * 48 + g * 8]) = outv[g];
    __syncthreads();
#pragma unroll
    for (int i = 0; i < 6; i++) {
        int c = tid + i * 192;
        *(ush8*)(gbase + c * 8) = *(const ush8*)(&s_in[c * 8]);
    }
    if (bx < 192 && tid < 4) {
        float s = 0.f;
        for (int i = 0; i < 48; i++) s += s_part[tid * 48 + i];
        sumsq[b * 768 + bx * 4 + tid] = s;
    }
}

// ---------------- K5: attn via MFMA, split-K over 8 waves; OUT: bf16 [c][d]; inline rsqrt ---
__global__ __launch_bounds__(512) void k_attn(const u16* __restrict__ qkv,
                                              const float* __restrict__ sumsq,
                                              const float* __restrict__ temp,
                                              u16* __restrict__ attn) {
    __shared__ float s_part[8][48 * 48];
    int h = blockIdx.x, b = blockIdx.y, tid = threadIdx.x;
    int wave = tid >> 6, lane = tid & 63;
    int lr = lane & 15, lk = lane >> 4;
    const u16* qp = qkv + ((size_t)b * QCH + h * 48) * NSP;
    const u16* kp = qkv + ((size_t)b * QCH + 384 + h * 48) * NSP;
    f32x4 acc[3][3];
#pragma unroll
    for (int m = 0; m < 3; m++)
#pragma unroll
        for (int n = 0; n < 3; n++) acc[m][n] = (f32x4){0.f, 0.f, 0.f, 0.f};
    int k0 = wave * 288 + lk * 8;
    short8 af[3], bf[3], afn[3], bfn[3];
#pragma unroll
    for (int m = 0; m < 3; m++) {
        af[m] = *(const short8*)(qp + (size_t)(m * 16 + lr) * NSP + k0);
        bf[m] = *(const short8*)(kp + (size_t)(m * 16 + lr) * NSP + k0);
    }
    for (int s = 0; s < 9; s++) {
        if (s < 8) {
#pragma unroll
            for (int m = 0; m < 3; m++) {
                afn[m] = *(const short8*)(qp + (size_t)(m * 16 + lr) * NSP + k0 + 32 * (s + 1));
                bfn[m] = *(const short8*)(kp + (size_t)(m * 16 + lr) * NSP + k0 + 32 * (s + 1));
            }
        }
#pragma unroll
        for (int m = 0; m < 3; m++)
#pragma unroll
            for (int n = 0; n < 3; n++)
                acc[m][n] = __builtin_amdgcn_mfma_f32_16x16x32_bf16(
                    __builtin_bit_cast(bf16x8, af[m]), __builtin_bit_cast(bf16x8, bf[n]),
                    acc[m][n], 0, 0, 0);
#pragma unroll
        for (int m = 0; m < 3; m++) { af[m] = afn[m]; bf[m] = bfn[m]; }
    }
#pragma unroll
    for (int m = 0; m < 3; m++)
#pragma unroll
        for (int n = 0; n < 3; n++)
#pragma unroll
            for (int r = 0; r < 4; r++)
                s_part[wave][(m * 16 + lk * 4 + r) * 48 + n * 16 + lr] = acc[m][n][r];
    __syncthreads();
    float th = temp[h];
    const float* sqv = sumsq + b * 768 + h * 48;
    const float* skv = sumsq + b * 768 + 384 + h * 48;
    u16* ap = attn + ((size_t)(b * 8 + h)) * NSP;
    for (int f = tid; f < 2304; f += 512) {
        int c = f / 48, d = f % 48;
        float v = 0.f;
#pragma unroll
        for (int wv = 0; wv < 8; wv++) v += s_part[wv][f];
        float rq = 1.f / fmaxf(sqrtf(sqv[c]), 1e-12f);
        float rk = 1.f / fmaxf(sqrtf(skv[d]), 1e-12f);
        v *= th * rq * rk;
        ap[f] = f2b(fmaxf(v, 0.f));   // bf16, [c][d]
    }
}

// ---------------- K6: high-pass depthwise (3/5/7), merged single kernel ----------
template<int KS, int CH0, int NCH>
__device__ __forceinline__ void hp_body(int g, const u16* __restrict__ qkv,
                                        const float* __restrict__ wk,
                                        const float* __restrict__ bk,
                                        u16* __restrict__ hp) {
    constexpr int PAD = KS / 2;
    constexpr int NIN = 8 + 2 * PAD;
    int t = g * 256 + threadIdx.x;
    int y = t % 48;
    int rem = t / 48;
    int chl = rem % NCH;
    int b = rem / NCH;
    int ch = CH0 + chl;
    const u16* src = qkv + ((size_t)b * QCH + 768 + ch) * NSP;
    float bias = bk[chl];
    float acc[48];
#pragma unroll
    for (int i = 0; i < 48; i++) acc[i] = bias;
    for (int dy = 0; dy < KS; dy++) {
        int yy = y - PAD + dy;
        if (yy < 0 || yy >= 48) continue;
        ush8 r[6];
#pragma unroll
        for (int o = 0; o < 6; o++) r[o] = *(const ush8*)(src + yy * 48 + o * 8);
        float wr[KS];
#pragma unroll
        for (int dx = 0; dx < KS; dx++) wr[dx] = wk[chl * KS * KS + dy * KS + dx];
#pragma unroll
        for (int g2 = 0; g2 < 6; g2++) {
            float a[NIN];
#pragma unroll
            for (int j = 0; j < NIN; j++) {
                int xi = g2 * 8 - PAD + j;
                a[j] = (xi < 0 || xi >= 48) ? 0.f : b2f(r[xi >> 3][xi & 7]);
            }
#pragma unroll
            for (int x = 0; x < 8; x++) {
                float s = 0.f;
#pragma unroll
                for (int dx = 0; dx < KS; dx++) s += a[x + dx] * wr[dx];
                acc[g2 * 8 + x] += s;
            }
        }
    }
    u16* dst = hp + ((size_t)b * CDIM + ch) * NSP + y * 48;
#pragma unroll
    for (int g2 = 0; g2 < 6; g2++) {
        union { u16 u[8]; short8 v; } pk;
#pragma unroll
        for (int x = 0; x < 8; x++) pk.u[x] = f2b(acc[g2 * 8 + x]);
        *(short8*)(dst + g2 * 8) = pk.v;
    }
}

__global__ __launch_bounds__(256) void k_hp(const u16* __restrict__ qkv,
                                            const float* __restrict__ w3, const float* __restrict__ b3,
                                            const float* __restrict__ w5, const float* __restrict__ b5,
                                            const float* __restrict__ w7, const float* __restrict__ b7,
                                            u16* __restrict__ hp) {
    int g = blockIdx.x;
    if (g < 864)       hp_body<3, 0, 144>(g, qkv, w3, b3, hp);
    else if (g < 1728) hp_body<5, 144, 144>(g - 864, qkv, w5, b5, hp);
    else               hp_body<7, 288, 96>(g - 1728, qkv, w7, b7, hp);
}

// ---------------- K7 v2: adaptive avg pool, LDS-staged coalesced ----------------
__global__ __launch_bounds__(64) void k_pool(const u16* __restrict__ qkv,
                                             float* __restrict__ pooled) {
    int c = blockIdx.x, b = blockIdx.y, tid = threadIdx.x;
    int s = 2 * (c / 96) + 1;  // 1,3,5,7
    __shared__ u16 s_p[2304];
    __shared__ float rp[48][7];
    const u16* src = qkv + ((size_t)b * QCH + 768 + c) * NSP;
    for (int f = tid; f < 288; f += 64)
        *(ush8*)(&s_p[f * 8]) = *(const ush8*)(src + f * 8);
    __syncthreads();
    if (tid < 48) {
        for (int q = 0; q < s; q++) {
            int a = q * 48 / s, e = ((q + 1) * 48 + s - 1) / s;
            float sum = 0.f;
            for (int xx = a; xx < e; xx++) sum += b2f(s_p[tid * 48 + xx]);
            rp[tid][q] = sum / (float)(e - a);
        }
    }
    __syncthreads();
    if (tid < s * s) {
        int p = tid / s, q = tid % s;
        int a = p * 48 / s, e = ((p + 1) * 48 + s - 1) / s;
        float sum = 0.f;
        for (int r = a; r < e; r++) sum += rp[r][q];
        pooled[((size_t)b * CDIM + c) * 49 + tid] = sum / (float)(e - a);
    }
}

// ---------------- K8 v7 (RESTORED): persistent-ish attn@v; grid (4,8,32), 9 chunks ---------
__global__ __launch_bounds__(256) void k_out(const u16* __restrict__ qkv,
                                             const u16* __restrict__ attn,
                                             const float* __restrict__ sumsq,
                                             const u16* __restrict__ hp,
                                             const float* __restrict__ pooled,
                                             u16* __restrict__ tmpt) {
    int ncg = blockIdx.x, h = blockIdx.y, b = blockIdx.z, tid = threadIdx.x;
    __shared__ __align__(16) u16 s_at[48 * 72];   // [c][72], cols 48..63 zero-padded
    __shared__ __align__(16) u16 s_vt[64 * 72];   // [nn][72], cols 48..63 zero-padded
    __shared__ float s_pool[48 * 49];
    __shared__ float s_rq[48];
    int s = 2 * (h / 2) + 1, ss2 = s * s;
    // ---- one-time staging (consumed after first in-loop barrier) ----
    if (tid < 96) {            // s_at pad cols 48..63
        int c = tid >> 1, col8 = 48 + (tid & 1) * 8;
        *(ush8*)(&s_at[c * 72 + col8]) = (ush8)0;
    }
    if (tid < 128) {           // s_vt pad cols 48..63 (never overwritten in loop)
        int nn = tid >> 1, col8 = 48 + (tid & 1) * 8;
        *(ush8*)(&s_vt[nn * 72 + col8]) = (ush8)0;
    }
    const u16* ag = attn + ((size_t)(b * 8 + h)) * NSP;
    for (int f = tid; f < 288; f += 256) {
        int c = f / 6, j = f % 6;
        *(ush8*)(&s_at[c * 72 + j * 8]) = *(const ush8*)(ag + c * 48 + j * 8);
    }
    const float* psrc = pooled + ((size_t)b * CDIM + h * 48) * 49;
    for (int f = tid; f < 48 * ss2; f += 256) {
        int c = f / ss2, idx = f - c * ss2;
        s_pool[c * 49 + idx] = psrc[c * 49 + idx];
    }
    if (tid < 48) s_rq[tid] = 1.f / fmaxf(sqrtf(sumsq[b * 768 + h * 48 + tid]), 1e-12f);

    int wave = tid >> 6, lane = tid & 63, lr = lane & 15, lk = lane >> 4;
    const u16* vbase = qkv + ((size_t)b * QCH + 768 + h * 48) * NSP;
    const u16* qbase = qkv + ((size_t)b * QCH + h * 48) * NSP;
    const u16* hbase = hp + ((size_t)b * CDIM + h * 48) * NSP;
    const float inv = 0.14433756729740643f;  // 48^-0.5
    short8 afr[3][2];

    for (int it = 0; it < 9; it++) {
        int n0 = (ncg * 9 + it) * 64;
        // stage v transpose for this chunk (d<48 region only)
        for (int f = tid; f < 3072; f += 256) {
            int d = f >> 6, nn = f & 63;
            s_vt[nn * 72 + d] = vbase[(size_t)d * NSP + n0 + nn];
        }
        __syncthreads();
        if (it == 0) {
#pragma unroll
            for (int m = 0; m < 3; m++)
#pragma unroll
                for (int ks = 0; ks < 2; ks++)
                    afr[m][ks] = *(const short8*)(&s_at[(m * 16 + lr) * 72 + ks * 32 + lk * 8]);
        }
        short8 b0 = *(const short8*)(&s_vt[(wave * 16 + lr) * 72 + lk * 8]);
        short8 b1 = *(const short8*)(&s_vt[(wave * 16 + lr) * 72 + 32 + lk * 8]);
        f32x4 acc[3];
#pragma unroll
        for (int m = 0; m < 3; m++) {
            acc[m] = (f32x4){0.f, 0.f, 0.f, 0.f};
            acc[m] = __builtin_amdgcn_mfma_f32_16x16x32_bf16(
                __builtin_bit_cast(bf16x8, afr[m][0]), __builtin_bit_cast(bf16x8, b0),
                acc[m], 0, 0, 0);
            acc[m] = __builtin_amdgcn_mfma_f32_16x16x32_bf16(
                __builtin_bit_cast(bf16x8, afr[m][1]), __builtin_bit_cast(bf16x8, b1),
                acc[m], 0, 0, 0);
        }
        int nl_e = wave * 16 + lr;
        int n = n0 + nl_e;
        int y = n / 48, xx = n % 48;
        int iy0 = 0, iy1 = 0, ix0 = 0, ix1 = 0;
        float fy = 0.f, fx = 0.f;
        if (s > 1) {
            float syf = (y + 0.5f) * s * (1.f / 48.f) - 0.5f;
            iy0 = (int)floorf(syf); fy = syf - (float)iy0;
            iy1 = min(iy0 + 1, s - 1); iy0 = max(iy0, 0);
            float sxf = (xx + 0.5f) * s * (1.f / 48.f) - 0.5f;
            ix0 = (int)floorf(sxf); fx = sxf - (float)ix0;
            ix1 = min(ix0 + 1, s - 1); ix0 = max(ix0, 0);
        }
        const u16* qp = qbase + n;
        const u16* hq = hbase + n;
        u16* tp = tmpt + ((size_t)b * NSP + n) * CDIM + h * 48;
#pragma unroll
        for (int m = 0; m < 3; m++) {
            int cb = m * 16 + lk * 4;
            union { u16 u[4]; sh4 v; } pk;
#pragma unroll
            for (int r = 0; r < 4; r++) {
                int ch = cb + r;
                float qv = b2f(qp[(size_t)ch * NSP]);
                float hv = b2f(hq[(size_t)ch * NSP]);
                const float* P = &s_pool[ch * 49];
                float lp;
                if (s == 1) lp = P[0];
                else lp = (1.f - fy) * ((1.f - fx) * P[iy0 * s + ix0] + fx * P[iy0 * s + ix1])
                        + fy * ((1.f - fx) * P[iy1 * s + ix0] + fx * P[iy1 * s + ix1]);
                lp = fmaxf(lp, 0.f);
                pk.u[r] = f2b(inv * acc[m][r] + qv * s_rq[ch] * hv + lp);
            }
            *(sh4*)(tp + cb) = pk.v;
        }
        __syncthreads();   // protect s_vt before next chunk's writes
    }
}

extern "C" void kernel_launch(void* const* d_in, const int* in_sizes, int n_in,
                              void* d_out, int out_size, void* d_ws, size_t ws_size,
                              hipStream_t stream) {
    const float* x    = (const float*)d_in[0];
    const float* lnw  = (const float*)d_in[1];
    const float* lnb  = (const float*)d_in[2];
    const float* wqkv = (const float*)d_in[3];
    const float* wdw  = (const float*)d_in[4];
    const float* temp = (const float*)d_in[5];
    const float* w3   = (const float*)d_in[6];
    const float* b3   = (const float*)d_in[7];
    const float* w5   = (const float*)d_in[8];
    const float* b5   = (const float*)d_in[9];
    const float* w7   = (const float*)d_in[10];
    const float* b7   = (const float*)d_in[11];
    const float* wproj= (const float*)d_in[12];
    float* out = (float*)d_out;

    char* w = (char*)d_ws;
    const size_t SZ_XNT = (size_t)NB * NSP * CDIM * 2;   // 56,623,104  (xn; reused as tmpt)
    const size_t SZ_QKV = (size_t)NB * QCH * NSP * 2;    // 169,869,312
    u16* xnt      = (u16*)w;
    u16* qkvb     = (u16*)(w + SZ_XNT);                  // gemm out; dw3 in-place
    u16* hpb      = (u16*)(w + SZ_XNT + SZ_QKV);         // hp output
    char* tail    = w + SZ_XNT + SZ_QKV + (size_t)NB * CDIM * NSP * 2;
    float* sumsq  = (float*)tail;
    u16*  attnb   = (u16*)(sumsq + NB * 768);            // bf16 [c][d]
    float* pooled = (float*)(attnb + (size_t)NB * 8 * NSP);
    u16* wqkv_bf  = (u16*)(pooled + (size_t)NB * CDIM * 49);
    u16* wproj_bf = wqkv_bf + (size_t)QCH * CDIM;
    u16* tmpt = xnt;

    k_prep <<<dim3((QCH * CDIM + 255) / 256), 256, 0, stream>>>(wqkv, wproj, wqkv_bf, wproj_bf);
    k_ln   <<<dim3(36, NB), 256, 0, stream>>>(x, lnw, lnb, xnt);
    k_gemm <<<dim3(18, 9, NB), 256, 0, stream>>>(wqkv_bf, xnt, qkvb, QCH, 0);
    k_dw3  <<<dim3(288, NB), 192, 0, stream>>>(qkvb, wdw, sumsq);
    k_attn <<<dim3(8, NB), 512, 0, stream>>>(qkvb, sumsq, temp, attnb);
    k_hp   <<<dim3(2304), 256, 0, stream>>>(qkvb, w3, b3, w5, b5, w7, b7, hpb);
    k_pool <<<dim3(CDIM, NB), 64, 0, stream>>>(qkvb, pooled);
    k_out  <<<dim3(4, 8, NB), 256, 0, stream>>>(qkvb, attnb, sumsq, hpb, pooled, tmpt);
    k_gemm <<<dim3(18, 3, NB), 256, 0, stream>>>(wproj_bf, tmpt, out, CDIM, 1);
}